// Round 18
// baseline (266.552 us; speedup 1.0000x reference)
//
#include <hip/hip_runtime.h>
#include <hip/hip_bf16.h>

typedef __bf16 bf16x8 __attribute__((ext_vector_type(8)));
typedef float f32x4 __attribute__((ext_vector_type(4)));
typedef unsigned short u16;
typedef unsigned int u32;

#define DEVI __device__ __forceinline__
#define EXP2(x) __builtin_amdgcn_exp2f(x)
#define MFMA16(a, b, c) __builtin_amdgcn_mfma_f32_16x16x32_bf16(a, b, c, 0, 0, 0)

DEVI u16 f2bf(float f) {
  union { float f; u32 u; } v; v.f = f;
  u32 r = v.u + 0x7FFFu + ((v.u >> 16) & 1u);
  return (u16)(r >> 16);
}
DEVI u16 f2bf_t(float f) {  // truncating (P in [0,1]: err <= 2^-8 * P)
  union { float f; u32 u; } v; v.f = f;
  return (u16)(v.u >> 16);
}
DEVI bf16x8 ldg8(const u16* p) {
  union { int4 i; bf16x8 b; } u;
  u.i = *(const int4*)p;
  return u.b;
}
DEVI void gld16(const u16* g, u16* l) {
  __builtin_amdgcn_global_load_lds((const __attribute__((address_space(1))) u32*)g,
                                   (__attribute__((address_space(3))) u32*)l, 16, 0, 0);
}

constexpr float QSCALE = 0.125f * 1.44269504089f;  // 1/sqrt(dk) * log2(e)

// ---------------- f32 -> bf16 conversions (merged launches) ----------------
__global__ __launch_bounds__(256) void cvt_x2(const float* __restrict__ a,
                                              const float* __restrict__ bsrc,
                                              u16* __restrict__ oa, u16* __restrict__ ob) {
  const float* s = blockIdx.y ? bsrc : a;
  u16* d = blockIdx.y ? ob : oa;
  int i = (blockIdx.x * 256 + threadIdx.x) * 4;
  float4 f = *(const float4*)(s + i);
  ushort4 o;
  o.x = f2bf(f.x); o.y = f2bf(f.y); o.z = f2bf(f.z); o.w = f2bf(f.w);
  *(ushort4*)(d + i) = o;
}

__global__ __launch_bounds__(256) void cvt_w4(const float* __restrict__ w0, const float* __restrict__ w1,
                                              const float* __restrict__ w2, const float* __restrict__ w3,
                                              u16* __restrict__ o0, u16* __restrict__ o1,
                                              u16* __restrict__ o2, u16* __restrict__ o3) {
  int y = blockIdx.y;
  const float* s = (y == 0) ? w0 : (y == 1) ? w1 : (y == 2) ? w2 : w3;
  u16* d = (y == 0) ? o0 : (y == 1) ? o1 : (y == 2) ? o2 : o3;
  int i = (blockIdx.x * 256 + threadIdx.x) * 4;
  float4 f = *(const float4*)(s + i);
  ushort4 o;
  o.x = f2bf(f.x); o.y = f2bf(f.y); o.z = f2bf(f.z); o.w = f2bf(f.w);
  *(ushort4*)(d + i) = o;
}

// ------- fused QKV projection: C[i][j] = sum_k A[i][k]*W[j][k] + bias[j] ----
__global__ __launch_bounds__(256) void gemm_qkv(const u16* __restrict__ XQ,
                                                const u16* __restrict__ XKV,
                                                const u16* __restrict__ WQ,
                                                const u16* __restrict__ WK,
                                                const u16* __restrict__ WV,
                                                const float* __restrict__ bqp,
                                                const float* __restrict__ bkp,
                                                const float* __restrict__ bvp,
                                                u16* __restrict__ Qo,
                                                u16* __restrict__ Ko,
                                                u16* __restrict__ Vo) {
  constexpr int K = 1024, N = 1024;
  const int z = blockIdx.z;
  const u16* A = (z == 0) ? XQ : XKV;
  const u16* W = (z == 0) ? WQ : (z == 1) ? WK : WV;
  const float* bias = (z == 0) ? bqp : (z == 1) ? bkp : bvp;
  u16* C = (z == 0) ? Qo : (z == 1) ? Ko : Vo;
  const float scale = (z == 0) ? QSCALE : 1.0f;

  __shared__ u16 sA[128 * 32], sB[128 * 32];
  const int t = threadIdx.x, w = t >> 6, l = t & 63;
  const int wm = w >> 1, wn = w & 1;
  const int lr = l & 15, lk = (l >> 4) * 8, lg = (l >> 4) * 4;
  const int rowA0 = blockIdx.y * 128, colB0 = blockIdx.x * 128;
  const int srow = l >> 2, scol = (l & 3) * 8;
  const u16* gA0 = A + (size_t)(rowA0 + w * 32 + srow) * K + scol;
  const u16* gA1 = gA0 + (size_t)16 * K;
  const u16* gB0 = W + (size_t)(colB0 + w * 32 + srow) * K + scol;
  const u16* gB1 = gB0 + (size_t)16 * K;
  u16* lA0 = sA + w * 1024;
  u16* lA1 = sA + w * 1024 + 512;
  u16* lB0 = sB + w * 1024;
  u16* lB1 = sB + w * 1024 + 512;
  f32x4 acc[4][4] = {};
  for (int k0 = 0; k0 < K; k0 += 32) {
    __syncthreads();
    gld16(gA0 + k0, lA0);
    gld16(gA1 + k0, lA1);
    gld16(gB0 + k0, lB0);
    gld16(gB1 + k0, lB1);
    __syncthreads();
    bf16x8 af[4], bfr[4];
#pragma unroll
    for (int m = 0; m < 4; ++m)
      af[m] = *(const bf16x8*)(sA + (wm * 64 + m * 16 + lr) * 32 + lk);
#pragma unroll
    for (int n = 0; n < 4; ++n)
      bfr[n] = *(const bf16x8*)(sB + (wn * 64 + n * 16 + lr) * 32 + lk);
#pragma unroll
    for (int m = 0; m < 4; ++m)
#pragma unroll
      for (int n = 0; n < 4; ++n)
        acc[m][n] = MFMA16(af[m], bfr[n], acc[m][n]);
  }
#pragma unroll
  for (int m = 0; m < 4; ++m) {
    int row = rowA0 + wm * 64 + m * 16 + lg;
#pragma unroll
    for (int n = 0; n < 4; ++n) {
      int col = colB0 + wn * 64 + n * 16 + lr;
      float bs = bias[col];
#pragma unroll
      for (int r = 0; r < 4; ++r)
        C[(size_t)(row + r) * N + col] = f2bf((acc[m][n][r] + bs) * scale);
    }
  }
}

// ---------------- O projection: f32 out. BM=64, BN=128, BK=32, 512 blocks ---
__global__ __launch_bounds__(256) void gemm_o(const u16* __restrict__ A,
                                              const u16* __restrict__ W,
                                              const float* __restrict__ bias,
                                              float* __restrict__ Cv) {
  constexpr int K = 1024, N = 1024;
  __shared__ u16 sA[64 * 32], sB[128 * 32];
  const int t = threadIdx.x, w = t >> 6, l = t & 63;
  const int wm = w >> 1, wn = w & 1;
  const int lr = l & 15, lk = (l >> 4) * 8, lg = (l >> 4) * 4;
  const int rowA0 = blockIdx.y * 64, colB0 = blockIdx.x * 128;
  const int srow = l >> 2, scol = (l & 3) * 8;
  const u16* gA  = A + (size_t)(rowA0 + w * 16 + srow) * K + scol;
  const u16* gB0 = W + (size_t)(colB0 + w * 32 + srow) * K + scol;
  const u16* gB1 = gB0 + (size_t)16 * K;
  u16* lA  = sA + w * 512;
  u16* lB0 = sB + w * 1024;
  u16* lB1 = sB + w * 1024 + 512;
  f32x4 acc[2][4] = {};
  for (int k0 = 0; k0 < K; k0 += 32) {
    __syncthreads();
    gld16(gA + k0, lA);
    gld16(gB0 + k0, lB0);
    gld16(gB1 + k0, lB1);
    __syncthreads();
    bf16x8 af[2], bfr[4];
#pragma unroll
    for (int m = 0; m < 2; ++m)
      af[m] = *(const bf16x8*)(sA + (wm * 32 + m * 16 + lr) * 32 + lk);
#pragma unroll
    for (int n = 0; n < 4; ++n)
      bfr[n] = *(const bf16x8*)(sB + (wn * 64 + n * 16 + lr) * 32 + lk);
#pragma unroll
    for (int m = 0; m < 2; ++m)
#pragma unroll
      for (int n = 0; n < 4; ++n)
        acc[m][n] = MFMA16(af[m], bfr[n], acc[m][n]);
  }
#pragma unroll
  for (int m = 0; m < 2; ++m) {
    int row = rowA0 + wm * 32 + m * 16 + lg;
#pragma unroll
    for (int n = 0; n < 4; ++n) {
      int col = colB0 + wn * 64 + n * 16 + lr;
      float bs = bias[col];
#pragma unroll
      for (int r = 0; r < 4; ++r)
        Cv[(size_t)(row + r) * N + col] = acc[m][n][r] + bs;
    }
  }
}

// ---------------- fused causal attention, writes attn (f32) + O (bf16) ------
// grid: (qtile=32 reversed, h=16, b=2) = 1024 blocks -> 4 blocks/CU.
// R17 structure (swapped QK^T) + attn stored DIRECTLY from S registers:
// lane's (p0..p3) at keys kb+nf*16+kloc..+3 is one float4 nt store (exact
// f32), eliminating the sP->uint2->unpack->store path (-4 ds_reads, -16 VALU
// per lane-tile). sP retained only as the PV A-fragment shuttle.
__global__ __launch_bounds__(256) void attn_fused(const u16* __restrict__ Qb,
                                                  const u16* __restrict__ Kb,
                                                  const u16* __restrict__ Vb,
                                                  float* __restrict__ attn,
                                                  u16* __restrict__ Ob) {
  constexpr int Tn = 2048, Dn = 1024, LDK = 72;
  const int qt = 31 - blockIdx.x, h = blockIdx.y, b = blockIdx.z;
  const int t = threadIdx.x, w = t >> 6, l = t & 63;
  const int lr = l & 15, lk = (l >> 4) * 8, lg = (l >> 4) * 4;
  __shared__ u16 sKV[128 * LDK];
  __shared__ u16 sP[64 * LDK];
  u16* sK  = sKV;                 // pass 2: rows 0-63
  u16* sVt = sKV + 64 * LDK;      // pass 2: rows 64-127 ([dk][key])

  const u16* KgB = Kb + (size_t)b * Tn * Dn + h * 64;
  const u16* VgB = Vb + (size_t)b * Tn * Dn + h * 64;
  const int skey = t >> 3, skc = (t & 7) * 8;  // staging coords (32-row groups)

  // Q fragments for this wave's 16 rows (q = qt*64 + w*16 + lr)
  bf16x8 qf[2];
  {
    int row = b * Tn + qt * 64 + w * 16 + lr;
#pragma unroll
    for (int ks = 0; ks < 2; ++ks)
      qf[ks] = ldg8(Qb + (size_t)row * Dn + h * 64 + ks * 32 + lk);
  }

  const int nkt = qt + 1;           // 64-key tiles
  const int nkt2 = (qt + 2) >> 1;   // 128-key tiles (pass 1)
  const int qg = qt * 64 + w * 16 + lr;   // this lane's q row (swapped layout)
  const int kloc = (l >> 4) * 4;          // lane's key-local base within 16-blk
  float psum = 0.f;                        // per-lane partial (q = qg)
  int4 kr0, kr1, kr2, kr3, vr0, vr1;

  // ---- pass 1: 128 keys per barrier-pair; per-row sum of exp2(s) ----
  kr0 = *(const int4*)(KgB + (size_t)skey * Dn + skc);
  kr1 = *(const int4*)(KgB + (size_t)(32 + skey) * Dn + skc);
  kr2 = *(const int4*)(KgB + (size_t)(64 + skey) * Dn + skc);
  kr3 = *(const int4*)(KgB + (size_t)(96 + skey) * Dn + skc);
  for (int kt2 = 0; kt2 < nkt2; ++kt2) {
    __builtin_amdgcn_s_barrier();
    __builtin_amdgcn_sched_barrier(0);
    *(int4*)(sKV + skey * LDK + skc) = kr0;
    *(int4*)(sKV + (32 + skey) * LDK + skc) = kr1;
    *(int4*)(sKV + (64 + skey) * LDK + skc) = kr2;
    *(int4*)(sKV + (96 + skey) * LDK + skc) = kr3;
    if (kt2 + 1 < nkt2) {
      const u16* p = KgB + (size_t)((kt2 + 1) * 128) * Dn;
      kr0 = *(const int4*)(p + (size_t)skey * Dn + skc);
      kr1 = *(const int4*)(p + (size_t)(32 + skey) * Dn + skc);
      kr2 = *(const int4*)(p + (size_t)(64 + skey) * Dn + skc);
      kr3 = *(const int4*)(p + (size_t)(96 + skey) * Dn + skc);
    }
    asm volatile("s_waitcnt lgkmcnt(0)" ::: "memory");
    __builtin_amdgcn_s_barrier();
    __builtin_amdgcn_sched_barrier(0);
#pragma unroll
    for (int h64 = 0; h64 < 2; ++h64) {
      const int k64 = kt2 * 2 + h64;
      f32x4 s[4] = {};
#pragma unroll
      for (int nf = 0; nf < 4; ++nf)
#pragma unroll
        for (int ks = 0; ks < 2; ++ks) {
          bf16x8 kf = *(const bf16x8*)(sKV + (h64 * 64 + nf * 16 + lr) * LDK + ks * 32 + lk);
          s[nf] = MFMA16(kf, qf[ks], s[nf]);   // SWAPPED: C[key][q]
        }
      if (k64 < qt) {  // fully-valid 64-key half
#pragma unroll
        for (int nf = 0; nf < 4; ++nf)
          psum += EXP2(s[nf][0]) + EXP2(s[nf][1]) + EXP2(s[nf][2]) + EXP2(s[nf][3]);
      } else if (k64 == qt) {  // diagonal half: key = kb + nf*16 + kloc + r
        const int kb = k64 * 64;
#pragma unroll
        for (int nf = 0; nf < 4; ++nf)
#pragma unroll
          for (int r = 0; r < 4; ++r) {
            float e = EXP2(s[nf][r]);
            psum += (kb + nf * 16 + kloc + r <= qg) ? e : 0.f;
          }
      }
    }
  }

  // prologue loads for pass 2 tile 0 (land during the reduce below)
  kr0 = *(const int4*)(KgB + (size_t)skey * Dn + skc);
  kr1 = *(const int4*)(KgB + (size_t)(32 + skey) * Dn + skc);
  vr0 = *(const int4*)(VgB + (size_t)l * Dn + w * 8);
  vr1 = *(const int4*)(VgB + (size_t)l * Dn + (4 + w) * 8);

  // reduce across the 4 key-groups (lanes l, l^16, l^32, l^48 share q)
  float inv;
  {
    float v = psum;
    v += __shfl_xor(v, 16);
    v += __shfl_xor(v, 32);
    inv = __builtin_amdgcn_rcpf(v);
  }

  float* attnBH = attn + (size_t)(b * 16 + h) * Tn * Tn;
  f32x4 accO[4] = {};

  // ---- pass 2: S (swapped) -> direct f32 nt stores + sP b64 writes -> PV ---
  for (int kt = 0; kt < nkt; ++kt) {
    __builtin_amdgcn_s_barrier();        // A: all waves consumed sK/sVt of kt-1
    __builtin_amdgcn_sched_barrier(0);
    *(int4*)(sK + skey * LDK + skc) = kr0;
    *(int4*)(sK + (32 + skey) * LDK + skc) = kr1;
    {
      const u16* pv0 = (const u16*)&vr0;
      const u16* pv1 = (const u16*)&vr1;
#pragma unroll
      for (int j = 0; j < 8; ++j) {
        sVt[(w * 8 + j) * LDK + l] = pv0[j];
        sVt[((4 + w) * 8 + j) * LDK + l] = pv1[j];
      }
    }
    if (kt + 1 < nkt) {
      const u16* pk = KgB + (size_t)((kt + 1) * 64) * Dn;
      const u16* pv = VgB + (size_t)((kt + 1) * 64) * Dn;
      kr0 = *(const int4*)(pk + (size_t)skey * Dn + skc);
      kr1 = *(const int4*)(pk + (size_t)(32 + skey) * Dn + skc);
      vr0 = *(const int4*)(pv + (size_t)l * Dn + w * 8);
      vr1 = *(const int4*)(pv + (size_t)l * Dn + (4 + w) * 8);
    }
    asm volatile("s_waitcnt lgkmcnt(0)" ::: "memory");
    __builtin_amdgcn_s_barrier();        // B: sK/sVt visible to all waves
    __builtin_amdgcn_sched_barrier(0);
    const int kb = kt * 64;
    f32x4 s[4] = {};
#pragma unroll
    for (int nf = 0; nf < 4; ++nf)
#pragma unroll
      for (int ks = 0; ks < 2; ++ks) {
        bf16x8 kf = *(const bf16x8*)(sK + (nf * 16 + lr) * LDK + ks * 32 + lk);
        s[nf] = MFMA16(kf, qf[ks], s[nf]);   // SWAPPED: C[key][q]
      }
    // P: lane owns q = w*16+lr, keys nf*16 + kloc + (0..3) contiguous.
    // Store exact f32 P straight to attn (nt) + packed bf16 to sP for PV.
    u16* prow = sP + (size_t)(w * 16 + lr) * LDK + kloc;
    float* arow = attnBH + (size_t)(qt * 64 + w * 16 + lr) * Tn + kb + kloc;
    if (kt < qt) {
#pragma unroll
      for (int nf = 0; nf < 4; ++nf) {
        float p0 = EXP2(s[nf][0]) * inv, p1 = EXP2(s[nf][1]) * inv;
        float p2 = EXP2(s[nf][2]) * inv, p3 = EXP2(s[nf][3]) * inv;
        f32x4 o = {p0, p1, p2, p3};
        __builtin_nontemporal_store(o, (f32x4*)(arow + nf * 16));
        u32 lo = (u32)f2bf_t(p0) | ((u32)f2bf_t(p1) << 16);
        u32 hi = (u32)f2bf_t(p2) | ((u32)f2bf_t(p3) << 16);
        *(uint2*)(prow + nf * 16) = make_uint2(lo, hi);
      }
    } else {
#pragma unroll
      for (int nf = 0; nf < 4; ++nf) {
        const int kg0 = kb + nf * 16 + kloc;
        float p0 = (kg0 + 0 <= qg) ? EXP2(s[nf][0]) * inv : 0.f;
        float p1 = (kg0 + 1 <= qg) ? EXP2(s[nf][1]) * inv : 0.f;
        float p2 = (kg0 + 2 <= qg) ? EXP2(s[nf][2]) * inv : 0.f;
        float p3 = (kg0 + 3 <= qg) ? EXP2(s[nf][3]) * inv : 0.f;
        f32x4 o = {p0, p1, p2, p3};
        __builtin_nontemporal_store(o, (f32x4*)(arow + nf * 16));
        u32 lo = (u32)f2bf_t(p0) | ((u32)f2bf_t(p1) << 16);
        u32 hi = (u32)f2bf_t(p2) | ((u32)f2bf_t(p3) << 16);
        *(uint2*)(prow + nf * 16) = make_uint2(lo, hi);
      }
    }
    // no barrier: sP rows w*16..w*16+15 are written and read by wave w only
#pragma unroll
    for (int ks = 0; ks < 2; ++ks) {
      bf16x8 ap, bv[4];
      ap = *(const bf16x8*)(sP + (w * 16 + lr) * LDK + ks * 32 + lk);
#pragma unroll
      for (int nf = 0; nf < 4; ++nf)
        bv[nf] = *(const bf16x8*)(sVt + (nf * 16 + lr) * LDK + ks * 32 + lk);
#pragma unroll
      for (int nf = 0; nf < 4; ++nf)
        accO[nf] = MFMA16(ap, bv[nf], accO[nf]);
    }
  }

  // zero-fill columns beyond causal extent of this q-tile (non-temporal)
  {
    const int zstart = nkt * 64;
    if (zstart < Tn) {
      f32x4 z4 = {0.f, 0.f, 0.f, 0.f};
      for (int rr = 0; rr < 64; ++rr) {
        float* rp = attnBH + (size_t)(qt * 64 + rr) * Tn;
        for (int cc = zstart + 4 * t; cc < Tn; cc += 1024)
          __builtin_nontemporal_store(z4, (f32x4*)(rp + cc));
      }
    }
  }

  // O (bf16) into [B*T][D] at this head's column block (PV not swapped)
  {
    int row = b * Tn + qt * 64 + w * 16 + lg;
#pragma unroll
    for (int nf = 0; nf < 4; ++nf) {
      int col = h * 64 + nf * 16 + lr;
#pragma unroll
      for (int r = 0; r < 4; ++r)
        Ob[(size_t)(row + r) * Dn + col] = f2bf(accO[nf][r]);
    }
  }
}

extern "C" void kernel_launch(void* const* d_in, const int* in_sizes, int n_in,
                              void* d_out, int out_size, void* d_ws, size_t ws_size,
                              hipStream_t stream) {
  const float* xq  = (const float*)d_in[0];
  const float* xkv = (const float*)d_in[1];
  // d_in[2] = mask (causal, implicit)
  const float* Wq = (const float*)d_in[3];
  const float* bq = (const float*)d_in[4];
  const float* Wk = (const float*)d_in[5];
  const float* bk = (const float*)d_in[6];
  const float* Wv = (const float*)d_in[7];
  const float* bv = (const float*)d_in[8];
  const float* Wo = (const float*)d_in[9];
  const float* bo = (const float*)d_in[10];

  float* out  = (float*)d_out;                  // [4096][1024]
  float* attn = out + (size_t)4096 * 1024;      // [2][16][2048][2048]

  u16* XQ  = (u16*)d_ws;
  u16* XKV = XQ  + (size_t)4096 * 1024;
  u16* WQb = XKV + (size_t)4096 * 1024;
  u16* WKb = WQb + (size_t)1024 * 1024;
  u16* WVb = WKb + (size_t)1024 * 1024;
  u16* WOb = WVb + (size_t)1024 * 1024;
  u16* Qb  = WOb + (size_t)1024 * 1024;
  u16* Kb  = Qb  + (size_t)4096 * 1024;
  u16* Vb  = Kb  + (size_t)4096 * 1024;
  u16* Ob  = Vb  + (size_t)4096 * 1024;

  cvt_x2<<<dim3(4096, 2), 256, 0, stream>>>(xq, xkv, XQ, XKV);
  cvt_w4<<<dim3(1024, 4), 256, 0, stream>>>(Wq, Wk, Wv, Wo, WQb, WKb, WVb, WOb);

  gemm_qkv<<<dim3(8, 32, 3), 256, 0, stream>>>(XQ, XKV, WQb, WKb, WVb,
                                               bq, bk, bv, Qb, Kb, Vb);

  attn_fused<<<dim3(32, 16, 2), 256, 0, stream>>>(Qb, Kb, Vb, attn, Ob);

  gemm_o<<<dim3(8, 64), 256, 0, stream>>>(Ob, WOb, bo, out);
}

// Round 19
// 232.755 us; speedup vs baseline: 1.1452x; 1.1452x over previous
//
#include <hip/hip_runtime.h>
#include <hip/hip_bf16.h>

typedef __bf16 bf16x8 __attribute__((ext_vector_type(8)));
typedef float f32x4 __attribute__((ext_vector_type(4)));
typedef unsigned short u16;
typedef unsigned int u32;

#define DEVI __device__ __forceinline__
#define EXP2(x) __builtin_amdgcn_exp2f(x)
#define MFMA16(a, b, c) __builtin_amdgcn_mfma_f32_16x16x32_bf16(a, b, c, 0, 0, 0)

DEVI u16 f2bf(float f) {
  union { float f; u32 u; } v; v.f = f;
  u32 r = v.u + 0x7FFFu + ((v.u >> 16) & 1u);
  return (u16)(r >> 16);
}
DEVI u16 f2bf_t(float f) {  // truncating (P in [0,1]: err <= 2^-8 * P)
  union { float f; u32 u; } v; v.f = f;
  return (u16)(v.u >> 16);
}
DEVI float bf2f(u32 u) {
  union { u32 u; float f; } v; v.u = u << 16;
  return v.f;
}
DEVI bf16x8 ldg8(const u16* p) {
  union { int4 i; bf16x8 b; } u;
  u.i = *(const int4*)p;
  return u.b;
}
DEVI void gld16(const u16* g, u16* l) {
  __builtin_amdgcn_global_load_lds((const __attribute__((address_space(1))) u32*)g,
                                   (__attribute__((address_space(3))) u32*)l, 16, 0, 0);
}

constexpr float QSCALE = 0.125f * 1.44269504089f;  // 1/sqrt(dk) * log2(e)

// ---------------- f32 -> bf16 conversions (merged launches) ----------------
__global__ __launch_bounds__(256) void cvt_x2(const float* __restrict__ a,
                                              const float* __restrict__ bsrc,
                                              u16* __restrict__ oa, u16* __restrict__ ob) {
  const float* s = blockIdx.y ? bsrc : a;
  u16* d = blockIdx.y ? ob : oa;
  int i = (blockIdx.x * 256 + threadIdx.x) * 4;
  float4 f = *(const float4*)(s + i);
  ushort4 o;
  o.x = f2bf(f.x); o.y = f2bf(f.y); o.z = f2bf(f.z); o.w = f2bf(f.w);
  *(ushort4*)(d + i) = o;
}

__global__ __launch_bounds__(256) void cvt_w4(const float* __restrict__ w0, const float* __restrict__ w1,
                                              const float* __restrict__ w2, const float* __restrict__ w3,
                                              u16* __restrict__ o0, u16* __restrict__ o1,
                                              u16* __restrict__ o2, u16* __restrict__ o3) {
  int y = blockIdx.y;
  const float* s = (y == 0) ? w0 : (y == 1) ? w1 : (y == 2) ? w2 : w3;
  u16* d = (y == 0) ? o0 : (y == 1) ? o1 : (y == 2) ? o2 : o3;
  int i = (blockIdx.x * 256 + threadIdx.x) * 4;
  float4 f = *(const float4*)(s + i);
  ushort4 o;
  o.x = f2bf(f.x); o.y = f2bf(f.y); o.z = f2bf(f.z); o.w = f2bf(f.w);
  *(ushort4*)(d + i) = o;
}

// ------- fused QKV projection: C[i][j] = sum_k A[i][k]*W[j][k] + bias[j] ----
__global__ __launch_bounds__(256) void gemm_qkv(const u16* __restrict__ XQ,
                                                const u16* __restrict__ XKV,
                                                const u16* __restrict__ WQ,
                                                const u16* __restrict__ WK,
                                                const u16* __restrict__ WV,
                                                const float* __restrict__ bqp,
                                                const float* __restrict__ bkp,
                                                const float* __restrict__ bvp,
                                                u16* __restrict__ Qo,
                                                u16* __restrict__ Ko,
                                                u16* __restrict__ Vo) {
  constexpr int K = 1024, N = 1024;
  const int z = blockIdx.z;
  const u16* A = (z == 0) ? XQ : XKV;
  const u16* W = (z == 0) ? WQ : (z == 1) ? WK : WV;
  const float* bias = (z == 0) ? bqp : (z == 1) ? bkp : bvp;
  u16* C = (z == 0) ? Qo : (z == 1) ? Ko : Vo;
  const float scale = (z == 0) ? QSCALE : 1.0f;

  __shared__ u16 sA[128 * 32], sB[128 * 32];
  const int t = threadIdx.x, w = t >> 6, l = t & 63;
  const int wm = w >> 1, wn = w & 1;
  const int lr = l & 15, lk = (l >> 4) * 8, lg = (l >> 4) * 4;
  const int rowA0 = blockIdx.y * 128, colB0 = blockIdx.x * 128;
  const int srow = l >> 2, scol = (l & 3) * 8;
  const u16* gA0 = A + (size_t)(rowA0 + w * 32 + srow) * K + scol;
  const u16* gA1 = gA0 + (size_t)16 * K;
  const u16* gB0 = W + (size_t)(colB0 + w * 32 + srow) * K + scol;
  const u16* gB1 = gB0 + (size_t)16 * K;
  u16* lA0 = sA + w * 1024;
  u16* lA1 = sA + w * 1024 + 512;
  u16* lB0 = sB + w * 1024;
  u16* lB1 = sB + w * 1024 + 512;
  f32x4 acc[4][4] = {};
  for (int k0 = 0; k0 < K; k0 += 32) {
    __syncthreads();
    gld16(gA0 + k0, lA0);
    gld16(gA1 + k0, lA1);
    gld16(gB0 + k0, lB0);
    gld16(gB1 + k0, lB1);
    __syncthreads();
    bf16x8 af[4], bfr[4];
#pragma unroll
    for (int m = 0; m < 4; ++m)
      af[m] = *(const bf16x8*)(sA + (wm * 64 + m * 16 + lr) * 32 + lk);
#pragma unroll
    for (int n = 0; n < 4; ++n)
      bfr[n] = *(const bf16x8*)(sB + (wn * 64 + n * 16 + lr) * 32 + lk);
#pragma unroll
    for (int m = 0; m < 4; ++m)
#pragma unroll
      for (int n = 0; n < 4; ++n)
        acc[m][n] = MFMA16(af[m], bfr[n], acc[m][n]);
  }
#pragma unroll
  for (int m = 0; m < 4; ++m) {
    int row = rowA0 + wm * 64 + m * 16 + lg;
#pragma unroll
    for (int n = 0; n < 4; ++n) {
      int col = colB0 + wn * 64 + n * 16 + lr;
      float bs = bias[col];
#pragma unroll
      for (int r = 0; r < 4; ++r)
        C[(size_t)(row + r) * N + col] = f2bf((acc[m][n][r] + bs) * scale);
    }
  }
}

// ---------------- O projection: f32 out. BM=64, BN=128, BK=32, 512 blocks ---
__global__ __launch_bounds__(256) void gemm_o(const u16* __restrict__ A,
                                              const u16* __restrict__ W,
                                              const float* __restrict__ bias,
                                              float* __restrict__ Cv) {
  constexpr int K = 1024, N = 1024;
  __shared__ u16 sA[64 * 32], sB[128 * 32];
  const int t = threadIdx.x, w = t >> 6, l = t & 63;
  const int wm = w >> 1, wn = w & 1;
  const int lr = l & 15, lk = (l >> 4) * 8, lg = (l >> 4) * 4;
  const int rowA0 = blockIdx.y * 64, colB0 = blockIdx.x * 128;
  const int srow = l >> 2, scol = (l & 3) * 8;
  const u16* gA  = A + (size_t)(rowA0 + w * 16 + srow) * K + scol;
  const u16* gB0 = W + (size_t)(colB0 + w * 32 + srow) * K + scol;
  const u16* gB1 = gB0 + (size_t)16 * K;
  u16* lA  = sA + w * 512;
  u16* lB0 = sB + w * 1024;
  u16* lB1 = sB + w * 1024 + 512;
  f32x4 acc[2][4] = {};
  for (int k0 = 0; k0 < K; k0 += 32) {
    __syncthreads();
    gld16(gA + k0, lA);
    gld16(gB0 + k0, lB0);
    gld16(gB1 + k0, lB1);
    __syncthreads();
    bf16x8 af[2], bfr[4];
#pragma unroll
    for (int m = 0; m < 2; ++m)
      af[m] = *(const bf16x8*)(sA + (wm * 32 + m * 16 + lr) * 32 + lk);
#pragma unroll
    for (int n = 0; n < 4; ++n)
      bfr[n] = *(const bf16x8*)(sB + (wn * 64 + n * 16 + lr) * 32 + lk);
#pragma unroll
    for (int m = 0; m < 2; ++m)
#pragma unroll
      for (int n = 0; n < 4; ++n)
        acc[m][n] = MFMA16(af[m], bfr[n], acc[m][n]);
  }
#pragma unroll
  for (int m = 0; m < 2; ++m) {
    int row = rowA0 + wm * 32 + m * 16 + lg;
#pragma unroll
    for (int n = 0; n < 4; ++n) {
      int col = colB0 + wn * 64 + n * 16 + lr;
      float bs = bias[col];
#pragma unroll
      for (int r = 0; r < 4; ++r)
        Cv[(size_t)(row + r) * N + col] = acc[m][n][r] + bs;
    }
  }
}

// ---------------- fused causal attention, writes attn (f32) + O (bf16) ------
// grid: (qtile=32 reversed, h=16, b=2) = 1024 blocks -> 4 blocks/CU.
// R17 (best, 233.1us): swapped QK^T (mfma(K,Q)) -> lane holds 4 consecutive
// keys for one q row; P->sP via b64 writes; softmax reduce = 2 shfls; attn
// stores via sP re-tiling (coalesced 64B segments). Raw-barrier discipline.
__global__ __launch_bounds__(256) void attn_fused(const u16* __restrict__ Qb,
                                                  const u16* __restrict__ Kb,
                                                  const u16* __restrict__ Vb,
                                                  float* __restrict__ attn,
                                                  u16* __restrict__ Ob) {
  constexpr int Tn = 2048, Dn = 1024, LDK = 72;
  const int qt = 31 - blockIdx.x, h = blockIdx.y, b = blockIdx.z;
  const int t = threadIdx.x, w = t >> 6, l = t & 63;
  const int lr = l & 15, lk = (l >> 4) * 8, lg = (l >> 4) * 4;
  __shared__ u16 sKV[128 * LDK];
  __shared__ u16 sP[64 * LDK];
  u16* sK  = sKV;                 // pass 2: rows 0-63
  u16* sVt = sKV + 64 * LDK;      // pass 2: rows 64-127 ([dk][key])

  const u16* KgB = Kb + (size_t)b * Tn * Dn + h * 64;
  const u16* VgB = Vb + (size_t)b * Tn * Dn + h * 64;
  const int skey = t >> 3, skc = (t & 7) * 8;  // staging coords (32-row groups)

  // Q fragments for this wave's 16 rows (q = qt*64 + w*16 + lr)
  bf16x8 qf[2];
  {
    int row = b * Tn + qt * 64 + w * 16 + lr;
#pragma unroll
    for (int ks = 0; ks < 2; ++ks)
      qf[ks] = ldg8(Qb + (size_t)row * Dn + h * 64 + ks * 32 + lk);
  }

  const int nkt = qt + 1;           // 64-key tiles
  const int nkt2 = (qt + 2) >> 1;   // 128-key tiles (pass 1)
  const int qg = qt * 64 + w * 16 + lr;   // this lane's q row (swapped layout)
  const int kloc = (l >> 4) * 4;          // lane's key-local base within 16-blk
  float psum = 0.f;                        // per-lane partial (q = qg)
  int4 kr0, kr1, kr2, kr3, vr0, vr1;

  // ---- pass 1: 128 keys per barrier-pair; per-row sum of exp2(s) ----
  kr0 = *(const int4*)(KgB + (size_t)skey * Dn + skc);
  kr1 = *(const int4*)(KgB + (size_t)(32 + skey) * Dn + skc);
  kr2 = *(const int4*)(KgB + (size_t)(64 + skey) * Dn + skc);
  kr3 = *(const int4*)(KgB + (size_t)(96 + skey) * Dn + skc);
  for (int kt2 = 0; kt2 < nkt2; ++kt2) {
    __builtin_amdgcn_s_barrier();
    __builtin_amdgcn_sched_barrier(0);
    *(int4*)(sKV + skey * LDK + skc) = kr0;
    *(int4*)(sKV + (32 + skey) * LDK + skc) = kr1;
    *(int4*)(sKV + (64 + skey) * LDK + skc) = kr2;
    *(int4*)(sKV + (96 + skey) * LDK + skc) = kr3;
    if (kt2 + 1 < nkt2) {
      const u16* p = KgB + (size_t)((kt2 + 1) * 128) * Dn;
      kr0 = *(const int4*)(p + (size_t)skey * Dn + skc);
      kr1 = *(const int4*)(p + (size_t)(32 + skey) * Dn + skc);
      kr2 = *(const int4*)(p + (size_t)(64 + skey) * Dn + skc);
      kr3 = *(const int4*)(p + (size_t)(96 + skey) * Dn + skc);
    }
    asm volatile("s_waitcnt lgkmcnt(0)" ::: "memory");
    __builtin_amdgcn_s_barrier();
    __builtin_amdgcn_sched_barrier(0);
#pragma unroll
    for (int h64 = 0; h64 < 2; ++h64) {
      const int k64 = kt2 * 2 + h64;
      f32x4 s[4] = {};
#pragma unroll
      for (int nf = 0; nf < 4; ++nf)
#pragma unroll
        for (int ks = 0; ks < 2; ++ks) {
          bf16x8 kf = *(const bf16x8*)(sKV + (h64 * 64 + nf * 16 + lr) * LDK + ks * 32 + lk);
          s[nf] = MFMA16(kf, qf[ks], s[nf]);   // SWAPPED: C[key][q]
        }
      if (k64 < qt) {  // fully-valid 64-key half
#pragma unroll
        for (int nf = 0; nf < 4; ++nf)
          psum += EXP2(s[nf][0]) + EXP2(s[nf][1]) + EXP2(s[nf][2]) + EXP2(s[nf][3]);
      } else if (k64 == qt) {  // diagonal half: key = kb + nf*16 + kloc + r
        const int kb = k64 * 64;
#pragma unroll
        for (int nf = 0; nf < 4; ++nf)
#pragma unroll
          for (int r = 0; r < 4; ++r) {
            float e = EXP2(s[nf][r]);
            psum += (kb + nf * 16 + kloc + r <= qg) ? e : 0.f;
          }
      }
    }
  }

  // prologue loads for pass 2 tile 0 (land during the reduce below)
  kr0 = *(const int4*)(KgB + (size_t)skey * Dn + skc);
  kr1 = *(const int4*)(KgB + (size_t)(32 + skey) * Dn + skc);
  vr0 = *(const int4*)(VgB + (size_t)l * Dn + w * 8);
  vr1 = *(const int4*)(VgB + (size_t)l * Dn + (4 + w) * 8);

  // reduce across the 4 key-groups (lanes l, l^16, l^32, l^48 share q)
  float inv;
  {
    float v = psum;
    v += __shfl_xor(v, 16);
    v += __shfl_xor(v, 32);
    inv = __builtin_amdgcn_rcpf(v);
  }

  float* attnBH = attn + (size_t)(b * 16 + h) * Tn * Tn;
  f32x4 accO[4] = {};

  // ---- pass 2: recompute S (swapped), P -> sP via b64 writes, PV, stores ---
  for (int kt = 0; kt < nkt; ++kt) {
    __builtin_amdgcn_s_barrier();        // A: all waves consumed sK/sVt of kt-1
    __builtin_amdgcn_sched_barrier(0);
    *(int4*)(sK + skey * LDK + skc) = kr0;
    *(int4*)(sK + (32 + skey) * LDK + skc) = kr1;
    {
      const u16* pv0 = (const u16*)&vr0;
      const u16* pv1 = (const u16*)&vr1;
#pragma unroll
      for (int j = 0; j < 8; ++j) {
        sVt[(w * 8 + j) * LDK + l] = pv0[j];
        sVt[((4 + w) * 8 + j) * LDK + l] = pv1[j];
      }
    }
    if (kt + 1 < nkt) {
      const u16* pk = KgB + (size_t)((kt + 1) * 64) * Dn;
      const u16* pv = VgB + (size_t)((kt + 1) * 64) * Dn;
      kr0 = *(const int4*)(pk + (size_t)skey * Dn + skc);
      kr1 = *(const int4*)(pk + (size_t)(32 + skey) * Dn + skc);
      vr0 = *(const int4*)(pv + (size_t)l * Dn + w * 8);
      vr1 = *(const int4*)(pv + (size_t)l * Dn + (4 + w) * 8);
    }
    asm volatile("s_waitcnt lgkmcnt(0)" ::: "memory");
    __builtin_amdgcn_s_barrier();        // B: sK/sVt visible to all waves
    __builtin_amdgcn_sched_barrier(0);
    const int kb = kt * 64;
    f32x4 s[4] = {};
#pragma unroll
    for (int nf = 0; nf < 4; ++nf)
#pragma unroll
      for (int ks = 0; ks < 2; ++ks) {
        bf16x8 kf = *(const bf16x8*)(sK + (nf * 16 + lr) * LDK + ks * 32 + lk);
        s[nf] = MFMA16(kf, qf[ks], s[nf]);   // SWAPPED: C[key][q]
      }
    // P write: lane owns q = w*16+lr, keys nf*16 + kloc + (0..3) contiguous
    u16* prow = sP + (size_t)(w * 16 + lr) * LDK + kloc;
    if (kt < qt) {
#pragma unroll
      for (int nf = 0; nf < 4; ++nf) {
        u32 lo = (u32)f2bf_t(EXP2(s[nf][0]) * inv) | ((u32)f2bf_t(EXP2(s[nf][1]) * inv) << 16);
        u32 hi = (u32)f2bf_t(EXP2(s[nf][2]) * inv) | ((u32)f2bf_t(EXP2(s[nf][3]) * inv) << 16);
        *(uint2*)(prow + nf * 16) = make_uint2(lo, hi);
      }
    } else {
#pragma unroll
      for (int nf = 0; nf < 4; ++nf) {
        const int kg0 = kb + nf * 16 + kloc;
        float p0 = (kg0 + 0 <= qg) ? EXP2(s[nf][0]) * inv : 0.f;
        float p1 = (kg0 + 1 <= qg) ? EXP2(s[nf][1]) * inv : 0.f;
        float p2 = (kg0 + 2 <= qg) ? EXP2(s[nf][2]) * inv : 0.f;
        float p3 = (kg0 + 3 <= qg) ? EXP2(s[nf][3]) * inv : 0.f;
        u32 lo = (u32)f2bf_t(p0) | ((u32)f2bf_t(p1) << 16);
        u32 hi = (u32)f2bf_t(p2) | ((u32)f2bf_t(p3) << 16);
        *(uint2*)(prow + nf * 16) = make_uint2(lo, hi);
      }
    }
    // no barrier: sP rows w*16..w*16+15 are written and read by wave w only
#pragma unroll
    for (int ks = 0; ks < 2; ++ks) {
      bf16x8 ap, bv[4];
      ap = *(const bf16x8*)(sP + (w * 16 + lr) * LDK + ks * 32 + lk);
#pragma unroll
      for (int nf = 0; nf < 4; ++nf)
        bv[nf] = *(const bf16x8*)(sVt + (nf * 16 + lr) * LDK + ks * 32 + lk);
#pragma unroll
      for (int nf = 0; nf < 4; ++nf)
        accO[nf] = MFMA16(ap, bv[nf], accO[nf]);
    }
    // per-wave coalesced non-temporal f32 attn stores of this wave's 16 rows
#pragma unroll
    for (int i = 0; i < 4; ++i) {
      int fidx = i * 64 + l;
      int row = w * 16 + (fidx >> 4), c4 = fidx & 15;
      uint2 pk = *(const uint2*)(sP + row * LDK + c4 * 4);
      f32x4 o;
      o[0] = bf2f(pk.x & 0xffffu);
      o[1] = bf2f(pk.x >> 16);
      o[2] = bf2f(pk.y & 0xffffu);
      o[3] = bf2f(pk.y >> 16);
      __builtin_nontemporal_store(o, (f32x4*)(attnBH + (size_t)(qt * 64 + row) * Tn + kb + c4 * 4));
    }
  }

  // zero-fill columns beyond causal extent of this q-tile (non-temporal)
  {
    const int zstart = nkt * 64;
    if (zstart < Tn) {
      f32x4 z4 = {0.f, 0.f, 0.f, 0.f};
      for (int rr = 0; rr < 64; ++rr) {
        float* rp = attnBH + (size_t)(qt * 64 + rr) * Tn;
        for (int cc = zstart + 4 * t; cc < Tn; cc += 1024)
          __builtin_nontemporal_store(z4, (f32x4*)(rp + cc));
      }
    }
  }

  // O (bf16) into [B*T][D] at this head's column block (PV not swapped)
  {
    int row = b * Tn + qt * 64 + w * 16 + lg;
#pragma unroll
    for (int nf = 0; nf < 4; ++nf) {
      int col = h * 64 + nf * 16 + lr;
#pragma unroll
      for (int r = 0; r < 4; ++r)
        Ob[(size_t)(row + r) * Dn + col] = f2bf(accO[nf][r]);
    }
  }
}

extern "C" void kernel_launch(void* const* d_in, const int* in_sizes, int n_in,
                              void* d_out, int out_size, void* d_ws, size_t ws_size,
                              hipStream_t stream) {
  const float* xq  = (const float*)d_in[0];
  const float* xkv = (const float*)d_in[1];
  // d_in[2] = mask (causal, implicit)
  const float* Wq = (const float*)d_in[3];
  const float* bq = (const float*)d_in[4];
  const float* Wk = (const float*)d_in[5];
  const float* bk = (const float*)d_in[6];
  const float* Wv = (const float*)d_in[7];
  const float* bv = (const float*)d_in[8];
  const float* Wo = (const float*)d_in[9];
  const float* bo = (const float*)d_in[10];

  float* out  = (float*)d_out;                  // [4096][1024]
  float* attn = out + (size_t)4096 * 1024;      // [2][16][2048][2048]

  u16* XQ  = (u16*)d_ws;
  u16* XKV = XQ  + (size_t)4096 * 1024;
  u16* WQb = XKV + (size_t)4096 * 1024;
  u16* WKb = WQb + (size_t)1024 * 1024;
  u16* WVb = WKb + (size_t)1024 * 1024;
  u16* WOb = WVb + (size_t)1024 * 1024;
  u16* Qb  = WOb + (size_t)1024 * 1024;
  u16* Kb  = Qb  + (size_t)4096 * 1024;
  u16* Vb  = Kb  + (size_t)4096 * 1024;
  u16* Ob  = Vb  + (size_t)4096 * 1024;

  cvt_x2<<<dim3(4096, 2), 256, 0, stream>>>(xq, xkv, XQ, XKV);
  cvt_w4<<<dim3(1024, 4), 256, 0, stream>>>(Wq, Wk, Wv, Wo, WQb, WKb, WVb, WOb);

  gemm_qkv<<<dim3(8, 32, 3), 256, 0, stream>>>(XQ, XKV, WQb, WKb, WVb,
                                               bq, bk, bv, Qb, Kb, Vb);

  attn_fused<<<dim3(32, 16, 2), 256, 0, stream>>>(Qb, Kb, Vb, attn, Ob);

  gemm_o<<<dim3(8, 64), 256, 0, stream>>>(Ob, WOb, bo, out);
}